// Round 1
// baseline (658.357 us; speedup 1.0000x reference)
//
#include <hip/hip_runtime.h>
#include <hip/hip_bf16.h>
#include <math.h>

#define T_TOK 4096
#define D_DIM 1024
#define E_EXP 8
#define FF_DIM 4096
#define MAXROWS (T_TOK * 2)
#define ROWPAD 128
#define ROWCAP (MAXROWS + ROWPAD)

#define BM 128
#define BN 128
#define BK 32
#define LDSTR 40  // padded LDS row stride in bf16 elems (80B, 16B-aligned, spreads banks)

typedef unsigned short u16;
typedef __attribute__((ext_vector_type(8))) short bf16x8;
typedef __attribute__((ext_vector_type(4))) float f32x4;

__device__ __forceinline__ u16 f2bf(float f) {
    union { float f; unsigned u; } v; v.f = f;
    unsigned r = v.u + 0x7FFFu + ((v.u >> 16) & 1u);
    return (u16)(r >> 16);
}

// ---------------- small kernels ----------------

__global__ void k_init(int* cnt, float* probsum) {
    int i = threadIdx.x;
    if (i < E_EXP) { cnt[i] = 0; probsum[i] = 0.f; }
}

__global__ __launch_bounds__(256) void k_router(
    const float* __restrict__ x, const float* __restrict__ Wr,
    int* __restrict__ tok_e, float* __restrict__ tok_w,
    int* __restrict__ cnt, float* __restrict__ probsum)
{
    __shared__ float bp[E_EXP];
    __shared__ int   bc[E_EXP];
    const int tid = threadIdx.x;
    if (tid < E_EXP) { bp[tid] = 0.f; bc[tid] = 0; }
    __syncthreads();
    const int wave = tid >> 6, lane = tid & 63;
    const int t = blockIdx.x * 4 + wave;
    const float* xt = x + (size_t)t * D_DIM;
    float a[E_EXP] = {0.f,0.f,0.f,0.f,0.f,0.f,0.f,0.f};
    for (int j = lane; j < D_DIM; j += 64) {
        float xv = xt[j];
        #pragma unroll
        for (int e = 0; e < E_EXP; e++) a[e] = fmaf(xv, Wr[e * D_DIM + j], a[e]);
    }
    #pragma unroll
    for (int e = 0; e < E_EXP; e++) {
        #pragma unroll
        for (int off = 32; off; off >>= 1) a[e] += __shfl_xor(a[e], off, 64);
    }
    if (lane == 0) {
        float mx = a[0];
        #pragma unroll
        for (int e = 1; e < E_EXP; e++) mx = fmaxf(mx, a[e]);
        float p[E_EXP], s = 0.f;
        #pragma unroll
        for (int e = 0; e < E_EXP; e++) { p[e] = expf(a[e] - mx); s += p[e]; }
        float inv = 1.f / s;
        #pragma unroll
        for (int e = 0; e < E_EXP; e++) { p[e] *= inv; atomicAdd(&bp[e], p[e]); }
        int e0 = 0; float v0 = p[0];
        #pragma unroll
        for (int e = 1; e < E_EXP; e++) if (p[e] > v0) { v0 = p[e]; e0 = e; }
        int e1 = -1; float v1 = -1.f;
        #pragma unroll
        for (int e = 0; e < E_EXP; e++) if (e != e0 && p[e] > v1) { v1 = p[e]; e1 = e; }
        float sv = v0 + v1 + 1e-6f;
        tok_e[2*t] = e0; tok_e[2*t+1] = e1;
        tok_w[2*t] = v0 / sv; tok_w[2*t+1] = v1 / sv;
        atomicAdd(&bc[e0], 1); atomicAdd(&bc[e1], 1);
    }
    __syncthreads();
    if (tid < E_EXP) { atomicAdd(&cnt[tid], bc[tid]); atomicAdd(&probsum[tid], bp[tid]); }
}

__global__ void k_prefix(const int* __restrict__ cnt, const float* __restrict__ probsum,
                         int* __restrict__ basep, int* __restrict__ cursor,
                         float* __restrict__ out_lb)
{
    if (threadIdx.x == 0) {
        int b = 0; float lb = 0.f;
        for (int e = 0; e < E_EXP; e++) {
            basep[e] = b; b += cnt[e];
            lb += ((float)cnt[e] / (8192.f + 1e-6f)) * probsum[e];
        }
        *out_lb = lb * (float)E_EXP;
    }
    if (threadIdx.x < E_EXP) cursor[threadIdx.x] = 0;
}

__global__ void k_assign(const int* __restrict__ tok_e, const float* __restrict__ tok_w,
                         const int* __restrict__ basep, int* __restrict__ cursor,
                         int* __restrict__ row_token, int* __restrict__ row_slot,
                         float* __restrict__ row_weight)
{
    int t = blockIdx.x * blockDim.x + threadIdx.x;
    if (t >= T_TOK) return;
    #pragma unroll
    for (int k = 0; k < 2; k++) {
        int e = tok_e[2*t + k];
        int pos = basep[e] + atomicAdd(&cursor[e], 1);
        row_token[pos] = t; row_slot[pos] = k; row_weight[pos] = tok_w[2*t + k];
    }
}

// ---------------- pass 1: hg = silu(x@Wg + bg) * (x@W1 + b1), per expert ----------------

__global__ __launch_bounds__(256, 2) void k_pass1(
    const float* __restrict__ x,
    const float* __restrict__ W1, const float* __restrict__ b1v,
    const float* __restrict__ Wg, const float* __restrict__ bgv,
    const int* __restrict__ cnt, const int* __restrict__ basep,
    const int* __restrict__ row_token,
    u16* __restrict__ hg)
{
    const int e = blockIdx.z;
    const int count = cnt[e];
    const int m0 = blockIdx.y * BM;
    if (m0 >= count) return;
    const int n0 = blockIdx.x * BN;
    const int rbase = basep[e];

    __shared__ u16 As[BM][LDSTR];
    __shared__ u16 Bh[BN][LDSTR];
    __shared__ u16 Bg[BN][LDSTR];

    const int tid = threadIdx.x;
    const int lane = tid & 63;

    // A staging: thread covers row = tid>>1, k-half (tid&1)*16
    const int arow = tid >> 1;
    const int akh = (tid & 1) * 16;
    const int growA = m0 + arow;
    int tokA = 0;
    if (growA < count) tokA = row_token[rbase + growA];
    const float* aptr = x + (size_t)tokA * D_DIM + akh;

    // B staging: thread covers column n = tid&127 of matrix (tid>>7), all 32 k
    const int bn = tid & 127;
    const int bsel = tid >> 7;
    const float* Wsel = bsel ? Wg : W1;
    const float* bptr = Wsel + (size_t)e * D_DIM * FF_DIM + (size_t)(n0 + bn);
    u16 (* __restrict__ Bs)[LDSTR] = bsel ? Bg : Bh;

    const int wid = tid >> 6;
    const int wm = (wid >> 1) * 64;
    const int wn = (wid & 1) * 64;
    const int fr = lane & 15;
    const int fk = (lane >> 4) * 8;

    f32x4 acc_h[4][4], acc_g[4][4];
    const f32x4 z4 = {0.f, 0.f, 0.f, 0.f};
    #pragma unroll
    for (int i = 0; i < 4; i++)
        #pragma unroll
        for (int j = 0; j < 4; j++) { acc_h[i][j] = z4; acc_g[i][j] = z4; }

    for (int k0 = 0; k0 < D_DIM; k0 += BK) {
        // global loads to regs (overlap with previous iteration's tail)
        const f32x4* ap4 = (const f32x4*)(aptr + k0);
        f32x4 a0 = ap4[0], a1 = ap4[1], a2 = ap4[2], a3 = ap4[3];
        float bv[32];
        #pragma unroll
        for (int i = 0; i < 32; i++) bv[i] = bptr[(size_t)(k0 + i) * FF_DIM];

        __syncthreads();
        bf16x8 aw0, aw1;
        #pragma unroll
        for (int j = 0; j < 4; j++) {
            aw0[j]     = (short)f2bf(a0[j]);
            aw0[j + 4] = (short)f2bf(a1[j]);
            aw1[j]     = (short)f2bf(a2[j]);
            aw1[j + 4] = (short)f2bf(a3[j]);
        }
        *(bf16x8*)&As[arow][akh]     = aw0;
        *(bf16x8*)&As[arow][akh + 8] = aw1;
        #pragma unroll
        for (int c = 0; c < 4; c++) {
            bf16x8 bw;
            #pragma unroll
            for (int j = 0; j < 8; j++) bw[j] = (short)f2bf(bv[c * 8 + j]);
            *(bf16x8*)&Bs[bn][c * 8] = bw;
        }
        __syncthreads();

        bf16x8 af[4], bhf[4], bgf[4];
        #pragma unroll
        for (int i = 0; i < 4; i++) af[i] = *(const bf16x8*)&As[wm + i*16 + fr][fk];
        #pragma unroll
        for (int j = 0; j < 4; j++) {
            bhf[j] = *(const bf16x8*)&Bh[wn + j*16 + fr][fk];
            bgf[j] = *(const bf16x8*)&Bg[wn + j*16 + fr][fk];
        }
        #pragma unroll
        for (int i = 0; i < 4; i++)
            #pragma unroll
            for (int j = 0; j < 4; j++) {
                acc_h[i][j] = __builtin_amdgcn_mfma_f32_16x16x32_bf16(af[i], bhf[j], acc_h[i][j], 0, 0, 0);
                acc_g[i][j] = __builtin_amdgcn_mfma_f32_16x16x32_bf16(af[i], bgf[j], acc_g[i][j], 0, 0, 0);
            }
    }

    const float* b1p = b1v + (size_t)e * FF_DIM + n0;
    const float* bgp = bgv + (size_t)e * FF_DIM + n0;
    #pragma unroll
    for (int i = 0; i < 4; i++) {
        const int rl = wm + i * 16 + (lane >> 4) * 4;
        #pragma unroll
        for (int r = 0; r < 4; r++) {
            const int g = m0 + rl + r;
            if (g < count) {
                u16* orow = hg + (size_t)(rbase + g) * FF_DIM + n0;
                #pragma unroll
                for (int j = 0; j < 4; j++) {
                    const int col = wn + j * 16 + fr;
                    float hv = acc_h[i][j][r] + b1p[col];
                    float gv = acc_g[i][j][r] + bgp[col];
                    float sig = 1.f / (1.f + expf(-gv));
                    orow[col] = f2bf(gv * sig * hv);
                }
            }
        }
    }
}

// ---------------- pass 2: contrib[slot,token] = w * (hg @ W2 + b2) ----------------

__global__ __launch_bounds__(256, 2) void k_pass2(
    const u16* __restrict__ hg,
    const float* __restrict__ W2, const float* __restrict__ b2v,
    const int* __restrict__ cnt, const int* __restrict__ basep,
    const int* __restrict__ row_token, const int* __restrict__ row_slot,
    const float* __restrict__ row_weight,
    float* __restrict__ contrib)
{
    const int e = blockIdx.z;
    const int count = cnt[e];
    const int m0 = blockIdx.y * BM;
    if (m0 >= count) return;
    const int n0 = blockIdx.x * BN;
    const int rbase = basep[e];

    __shared__ u16 As[BM][LDSTR];
    __shared__ u16 Bs[BN][LDSTR];

    const int tid = threadIdx.x;
    const int lane = tid & 63;

    const int arow = tid >> 1;
    const int akh = (tid & 1) * 16;
    const u16* aptr = hg + (size_t)(rbase + m0 + arow) * FF_DIM + akh;

    const int bn = tid & 127;
    const int bkh = (tid >> 7) * 16;
    const float* bptr = W2 + (size_t)e * FF_DIM * D_DIM + (size_t)(n0 + bn);

    const int wid = tid >> 6;
    const int wm = (wid >> 1) * 64;
    const int wn = (wid & 1) * 64;
    const int fr = lane & 15;
    const int fk = (lane >> 4) * 8;

    f32x4 acc[4][4];
    const f32x4 z4 = {0.f, 0.f, 0.f, 0.f};
    #pragma unroll
    for (int i = 0; i < 4; i++)
        #pragma unroll
        for (int j = 0; j < 4; j++) acc[i][j] = z4;

    for (int k0 = 0; k0 < FF_DIM; k0 += BK) {
        bf16x8 aw0 = *(const bf16x8*)(aptr + k0);
        bf16x8 aw1 = *(const bf16x8*)(aptr + k0 + 8);
        float bv[16];
        #pragma unroll
        for (int i = 0; i < 16; i++) bv[i] = bptr[(size_t)(k0 + bkh + i) * D_DIM];

        __syncthreads();
        *(bf16x8*)&As[arow][akh]     = aw0;
        *(bf16x8*)&As[arow][akh + 8] = aw1;
        #pragma unroll
        for (int c = 0; c < 2; c++) {
            bf16x8 bw;
            #pragma unroll
            for (int j = 0; j < 8; j++) bw[j] = (short)f2bf(bv[c * 8 + j]);
            *(bf16x8*)&Bs[bn][bkh + c * 8] = bw;
        }
        __syncthreads();

        bf16x8 af[4], bf_[4];
        #pragma unroll
        for (int i = 0; i < 4; i++) af[i] = *(const bf16x8*)&As[wm + i*16 + fr][fk];
        #pragma unroll
        for (int j = 0; j < 4; j++) bf_[j] = *(const bf16x8*)&Bs[wn + j*16 + fr][fk];
        #pragma unroll
        for (int i = 0; i < 4; i++)
            #pragma unroll
            for (int j = 0; j < 4; j++)
                acc[i][j] = __builtin_amdgcn_mfma_f32_16x16x32_bf16(af[i], bf_[j], acc[i][j], 0, 0, 0);
    }

    const float* b2p = b2v + (size_t)e * D_DIM + n0;
    #pragma unroll
    for (int i = 0; i < 4; i++) {
        const int rl = wm + i * 16 + (lane >> 4) * 4;
        #pragma unroll
        for (int r = 0; r < 4; r++) {
            const int g = m0 + rl + r;
            if (g < count) {
                const int token = row_token[rbase + g];
                const int slot  = row_slot[rbase + g];
                const float w   = row_weight[rbase + g];
                float* orow = contrib + ((size_t)slot * T_TOK + token) * D_DIM + n0;
                #pragma unroll
                for (int j = 0; j < 4; j++) {
                    const int col = wn + j * 16 + fr;
                    orow[col] = w * (acc[i][j][r] + b2p[col]);
                }
            }
        }
    }
}

__global__ void k_combine(const float* __restrict__ contrib, float* __restrict__ out) {
    int i = blockIdx.x * blockDim.x + threadIdx.x;
    const f32x4* c0 = (const f32x4*)contrib;
    const f32x4* c1 = c0 + ((size_t)T_TOK * D_DIM / 4);
    f32x4* o = (f32x4*)out;
    o[i] = c0[i] + c1[i];
}

// ---------------- launch ----------------

extern "C" void kernel_launch(void* const* d_in, const int* in_sizes, int n_in,
                              void* d_out, int out_size, void* d_ws, size_t ws_size,
                              hipStream_t stream)
{
    (void)in_sizes; (void)n_in; (void)out_size; (void)ws_size;
    const float* x  = (const float*)d_in[0];
    const float* Wr = (const float*)d_in[1];
    const float* W1 = (const float*)d_in[2];
    const float* b1 = (const float*)d_in[3];
    const float* Wg = (const float*)d_in[4];
    const float* bg = (const float*)d_in[5];
    const float* W2 = (const float*)d_in[6];
    const float* b2 = (const float*)d_in[7];
    float* out = (float*)d_out;

    char* ws = (char*)d_ws;
    u16* hg = (u16*)ws;              ws += (size_t)ROWCAP * FF_DIM * sizeof(u16);
    float* contrib = (float*)ws;     ws += (size_t)2 * T_TOK * D_DIM * sizeof(float);
    int* tok_e = (int*)ws;           ws += (size_t)T_TOK * 2 * sizeof(int);
    float* tok_w = (float*)ws;       ws += (size_t)T_TOK * 2 * sizeof(float);
    int* row_token = (int*)ws;       ws += (size_t)ROWCAP * sizeof(int);
    int* row_slot = (int*)ws;        ws += (size_t)ROWCAP * sizeof(int);
    float* row_weight = (float*)ws;  ws += (size_t)ROWCAP * sizeof(float);
    int* cnt = (int*)ws;             ws += 8 * sizeof(int);
    int* basep = (int*)ws;           ws += 8 * sizeof(int);
    int* cursor = (int*)ws;          ws += 8 * sizeof(int);
    float* probsum = (float*)ws;     ws += 8 * sizeof(float);

    k_init<<<1, 64, 0, stream>>>(cnt, probsum);
    k_router<<<T_TOK / 4, 256, 0, stream>>>(x, Wr, tok_e, tok_w, cnt, probsum);
    k_prefix<<<1, 64, 0, stream>>>(cnt, probsum, basep, cursor, out + (size_t)T_TOK * D_DIM);
    k_assign<<<T_TOK / 256, 256, 0, stream>>>(tok_e, tok_w, basep, cursor, row_token, row_slot, row_weight);
    k_pass1<<<dim3(FF_DIM / BN, 32, E_EXP), 256, 0, stream>>>(x, W1, b1, Wg, bg, cnt, basep, row_token, hg);
    k_pass2<<<dim3(D_DIM / BN, 32, E_EXP), 256, 0, stream>>>(hg, W2, b2, cnt, basep, row_token, row_slot, row_weight, contrib);
    k_combine<<<(T_TOK * D_DIM / 4) / 256, 256, 0, stream>>>(contrib, out);
}

// Round 2
// 608.326 us; speedup vs baseline: 1.0822x; 1.0822x over previous
//
#include <hip/hip_runtime.h>
#include <hip/hip_bf16.h>
#include <math.h>

#define T_TOK 4096
#define D_DIM 1024
#define E_EXP 8
#define FF_DIM 4096
#define NROWS (T_TOK * 2)

typedef unsigned short u16;
typedef unsigned int u32;
typedef __attribute__((ext_vector_type(8))) short bf16x8;
typedef __attribute__((ext_vector_type(4))) float f32x4;
typedef __attribute__((ext_vector_type(4))) short s16x4;

__device__ __forceinline__ u16 f2bf(float f) {
    union { float f; unsigned u; } v; v.f = f;
    unsigned r = v.u + 0x7FFFu + ((v.u >> 16) & 1u);
    return (u16)(r >> 16);
}

typedef const __attribute__((address_space(1))) u32* gas1_t;
typedef __attribute__((address_space(3))) u32* las3_t;
#define GLOAD16(g, l) __builtin_amdgcn_global_load_lds((gas1_t)(const void*)(g), (las3_t)(void*)(l), 16, 0, 0)

// ---------------- small kernels ----------------

__global__ void k_init(int* cnt, float* probsum) {
    int i = threadIdx.x;
    if (i < E_EXP) { cnt[i] = 0; probsum[i] = 0.f; }
}

__global__ __launch_bounds__(256) void k_router(
    const float* __restrict__ x, const float* __restrict__ Wr,
    int* __restrict__ tok_e, float* __restrict__ tok_w,
    int* __restrict__ cnt, float* __restrict__ probsum)
{
    __shared__ float bp[E_EXP];
    __shared__ int   bc[E_EXP];
    const int tid = threadIdx.x;
    if (tid < E_EXP) { bp[tid] = 0.f; bc[tid] = 0; }
    __syncthreads();
    const int wave = tid >> 6, lane = tid & 63;
    const int t = blockIdx.x * 4 + wave;
    const float* xt = x + (size_t)t * D_DIM;
    float a[E_EXP] = {0.f,0.f,0.f,0.f,0.f,0.f,0.f,0.f};
    for (int j = lane; j < D_DIM; j += 64) {
        float xv = xt[j];
        #pragma unroll
        for (int e = 0; e < E_EXP; e++) a[e] = fmaf(xv, Wr[e * D_DIM + j], a[e]);
    }
    #pragma unroll
    for (int e = 0; e < E_EXP; e++) {
        #pragma unroll
        for (int off = 32; off; off >>= 1) a[e] += __shfl_xor(a[e], off, 64);
    }
    if (lane == 0) {
        float mx = a[0];
        #pragma unroll
        for (int e = 1; e < E_EXP; e++) mx = fmaxf(mx, a[e]);
        float p[E_EXP], s = 0.f;
        #pragma unroll
        for (int e = 0; e < E_EXP; e++) { p[e] = expf(a[e] - mx); s += p[e]; }
        float inv = 1.f / s;
        #pragma unroll
        for (int e = 0; e < E_EXP; e++) { p[e] *= inv; atomicAdd(&bp[e], p[e]); }
        int e0 = 0; float v0 = p[0];
        #pragma unroll
        for (int e = 1; e < E_EXP; e++) if (p[e] > v0) { v0 = p[e]; e0 = e; }
        int e1 = -1; float v1 = -1.f;
        #pragma unroll
        for (int e = 0; e < E_EXP; e++) if (e != e0 && p[e] > v1) { v1 = p[e]; e1 = e; }
        float sv = v0 + v1 + 1e-6f;
        tok_e[2*t] = e0; tok_e[2*t+1] = e1;
        tok_w[2*t] = v0 / sv; tok_w[2*t+1] = v1 / sv;
        atomicAdd(&bc[e0], 1); atomicAdd(&bc[e1], 1);
    }
    __syncthreads();
    if (tid < E_EXP) { atomicAdd(&cnt[tid], bc[tid]); atomicAdd(&probsum[tid], bp[tid]); }
}

__global__ void k_prefix(const int* __restrict__ cnt, const float* __restrict__ probsum,
                         int* __restrict__ basep, int* __restrict__ cursor,
                         float* __restrict__ out_lb)
{
    if (threadIdx.x == 0) {
        int b = 0; float lb = 0.f;
        for (int e = 0; e < E_EXP; e++) {
            basep[e] = b; b += cnt[e];
            lb += ((float)cnt[e] / (8192.f + 1e-6f)) * probsum[e];
        }
        *out_lb = lb * (float)E_EXP;
    }
    if (threadIdx.x < E_EXP) cursor[threadIdx.x] = 0;
}

__global__ void k_assign(const int* __restrict__ tok_e, const float* __restrict__ tok_w,
                         const int* __restrict__ basep, int* __restrict__ cursor,
                         int* __restrict__ row_token, int* __restrict__ row_slot,
                         float* __restrict__ row_weight)
{
    int t = blockIdx.x * blockDim.x + threadIdx.x;
    if (t >= T_TOK) return;
    #pragma unroll
    for (int k = 0; k < 2; k++) {
        int e = tok_e[2*t + k];
        int pos = basep[e] + atomicAdd(&cursor[e], 1);
        row_token[pos] = t; row_slot[pos] = k; row_weight[pos] = tok_w[2*t + k];
    }
}

// ---------------- conversion kernels ----------------

// x fp32 [T][D] -> bf16 same layout
__global__ __launch_bounds__(256) void k_cvt_x(const float* __restrict__ in, u16* __restrict__ out) {
    size_t i = ((size_t)blockIdx.x * 256 + threadIdx.x) * 8;
    f32x4 a = *(const f32x4*)(in + i);
    f32x4 b = *(const f32x4*)(in + i + 4);
    bf16x8 o;
    #pragma unroll
    for (int j = 0; j < 4; j++) { o[j] = (short)f2bf(a[j]); o[j + 4] = (short)f2bf(b[j]); }
    *(bf16x8*)(out + i) = o;
}

// fp32 [R][C] tile-transposed to bf16 [C][R]
__device__ __forceinline__ void tile_transpose(const float* __restrict__ in, u16* __restrict__ out,
                                               int R, int C) {
    __shared__ u16 t[64][68];
    const int r0 = blockIdx.y * 64, c0 = blockIdx.x * 64;
    const int tid = threadIdx.x;
    const int lr = tid >> 4, lc = (tid & 15) * 4;
    #pragma unroll
    for (int i = 0; i < 4; i++) {
        const int r = lr + i * 16;
        f32x4 v = *(const f32x4*)(in + (size_t)(r0 + r) * C + c0 + lc);
        s16x4 w;
        #pragma unroll
        for (int j = 0; j < 4; j++) w[j] = (short)f2bf(v[j]);
        *(s16x4*)&t[r][lc] = w;
    }
    __syncthreads();
    #pragma unroll
    for (int i = 0; i < 4; i++) {
        const int c = lr + i * 16;
        s16x4 w;
        #pragma unroll
        for (int j = 0; j < 4; j++) w[j] = (short)t[lc + j][c];
        *(s16x4*)(out + (size_t)(c0 + c) * R + r0 + lc) = w;
    }
}

// W1/Wg: fp32 [E][D][FF] -> bf16 [E][FF][D]; z<8 -> W1, z>=8 -> Wg
__global__ __launch_bounds__(256) void k_cvt_wt(const float* __restrict__ W1, const float* __restrict__ Wg,
                                                u16* __restrict__ w1t, u16* __restrict__ wgt) {
    const int z = blockIdx.z;
    const float* in;
    u16* out;
    if (z < E_EXP) { in = W1 + (size_t)z * D_DIM * FF_DIM; out = w1t + (size_t)z * D_DIM * FF_DIM; }
    else { in = Wg + (size_t)(z - E_EXP) * D_DIM * FF_DIM; out = wgt + (size_t)(z - E_EXP) * D_DIM * FF_DIM; }
    tile_transpose(in, out, D_DIM, FF_DIM);
}

// W2: fp32 [E][FF][D] -> bf16 [E][D][FF]
__global__ __launch_bounds__(256) void k_cvt_w2(const float* __restrict__ W2, u16* __restrict__ w2t) {
    const int z = blockIdx.z;
    tile_transpose(W2 + (size_t)z * FF_DIM * D_DIM, w2t + (size_t)z * FF_DIM * D_DIM, FF_DIM, D_DIM);
}

// ---------------- pass 1: hg = silu(x@Wg + bg) * (x@W1 + b1) ----------------
// m97 structure: global_load_lds(16B) staging, 2-barrier K-loop, BK=32, 128x128 tile.

__global__ __launch_bounds__(256, 2) void k_pass1(
    const u16* __restrict__ xbf,
    const u16* __restrict__ w1t, const u16* __restrict__ wgt,
    const float* __restrict__ b1v, const float* __restrict__ bgv,
    const int* __restrict__ cnt, const int* __restrict__ basep,
    const int* __restrict__ row_token,
    u16* __restrict__ hg)
{
    const int e = blockIdx.z;
    const int count = cnt[e];
    const int m0 = blockIdx.y * 128;
    if (m0 >= count) return;
    const int n0 = blockIdx.x * 128;
    const int rbase = basep[e];

    __shared__ u16 As[128 * 32];
    __shared__ u16 Bh[128 * 32];
    __shared__ u16 Bg[128 * 32];

    const int tid = threadIdx.x;
    const int lane = tid & 63;
    const int wid = tid >> 6;

    // staging: chunk ch covers 16 rows; lane -> row ch*16 + (lane>>2), k-quarter (lane&3)*8
    const int kq = (lane & 3) * 8;
    const u16* aSrc[2]; const u16* bhSrc[2]; const u16* bgSrc[2];
    u16* aDst[2]; u16* bhDst[2]; u16* bgDst[2];
    #pragma unroll
    for (int i = 0; i < 2; i++) {
        const int ch = wid * 2 + i;
        const int row = ch * 16 + (lane >> 2);
        int g = m0 + row; if (g > count - 1) g = count - 1;
        const int tok = row_token[rbase + g];
        aSrc[i] = xbf + (size_t)tok * D_DIM + kq;
        const size_t wo = ((size_t)e * FF_DIM + (size_t)(n0 + row)) * D_DIM + kq;
        bhSrc[i] = w1t + wo;
        bgSrc[i] = wgt + wo;
        aDst[i]  = &As[ch * 512];
        bhDst[i] = &Bh[ch * 512];
        bgDst[i] = &Bg[ch * 512];
    }

    const int wm = (wid >> 1) * 64;
    const int wn = (wid & 1) * 64;
    const int fr = lane & 15;
    const int fk = (lane >> 4) * 8;

    f32x4 acc_h[4][4], acc_g[4][4];
    const f32x4 z4 = {0.f, 0.f, 0.f, 0.f};
    #pragma unroll
    for (int i = 0; i < 4; i++)
        #pragma unroll
        for (int j = 0; j < 4; j++) { acc_h[i][j] = z4; acc_g[i][j] = z4; }

    for (int k0 = 0; k0 < D_DIM; k0 += 32) {
        __syncthreads();
        #pragma unroll
        for (int i = 0; i < 2; i++) {
            GLOAD16(aSrc[i] + k0, aDst[i]);
            GLOAD16(bhSrc[i] + k0, bhDst[i]);
            GLOAD16(bgSrc[i] + k0, bgDst[i]);
        }
        __syncthreads();

        bf16x8 af[4], bhf[4], bgf[4];
        #pragma unroll
        for (int i = 0; i < 4; i++) af[i] = *(const bf16x8*)&As[(wm + i * 16 + fr) * 32 + fk];
        #pragma unroll
        for (int j = 0; j < 4; j++) {
            bhf[j] = *(const bf16x8*)&Bh[(wn + j * 16 + fr) * 32 + fk];
            bgf[j] = *(const bf16x8*)&Bg[(wn + j * 16 + fr) * 32 + fk];
        }
        #pragma unroll
        for (int i = 0; i < 4; i++)
            #pragma unroll
            for (int j = 0; j < 4; j++) {
                acc_h[i][j] = __builtin_amdgcn_mfma_f32_16x16x32_bf16(af[i], bhf[j], acc_h[i][j], 0, 0, 0);
                acc_g[i][j] = __builtin_amdgcn_mfma_f32_16x16x32_bf16(af[i], bgf[j], acc_g[i][j], 0, 0, 0);
            }
    }

    const float* b1p = b1v + (size_t)e * FF_DIM + n0;
    const float* bgp = bgv + (size_t)e * FF_DIM + n0;
    #pragma unroll
    for (int i = 0; i < 4; i++) {
        const int rl = wm + i * 16 + (lane >> 4) * 4;
        #pragma unroll
        for (int r = 0; r < 4; r++) {
            const int g = m0 + rl + r;
            if (g < count) {
                u16* orow = hg + (size_t)(rbase + g) * FF_DIM + n0;
                #pragma unroll
                for (int j = 0; j < 4; j++) {
                    const int col = wn + j * 16 + fr;
                    float hv = acc_h[i][j][r] + b1p[col];
                    float gv = acc_g[i][j][r] + bgp[col];
                    float sig = 1.f / (1.f + expf(-gv));
                    orow[col] = f2bf(gv * sig * hv);
                }
            }
        }
    }
}

// ---------------- pass 2: contrib[slot,token] = w * (hg @ W2 + b2) ----------------

__global__ __launch_bounds__(256, 3) void k_pass2(
    const u16* __restrict__ hg,
    const u16* __restrict__ w2t, const float* __restrict__ b2v,
    const int* __restrict__ cnt, const int* __restrict__ basep,
    const int* __restrict__ row_token, const int* __restrict__ row_slot,
    const float* __restrict__ row_weight,
    float* __restrict__ contrib)
{
    const int e = blockIdx.z;
    const int count = cnt[e];
    const int m0 = blockIdx.y * 128;
    if (m0 >= count) return;
    const int n0 = blockIdx.x * 128;
    const int rbase = basep[e];

    __shared__ u16 As[128 * 32];
    __shared__ u16 Bs[128 * 32];

    const int tid = threadIdx.x;
    const int lane = tid & 63;
    const int wid = tid >> 6;

    const int kq = (lane & 3) * 8;
    const u16* aSrc[2]; const u16* bSrc[2];
    u16* aDst[2]; u16* bDst[2];
    #pragma unroll
    for (int i = 0; i < 2; i++) {
        const int ch = wid * 2 + i;
        const int row = ch * 16 + (lane >> 2);
        int g = m0 + row; if (g > count - 1) g = count - 1;
        aSrc[i] = hg + (size_t)(rbase + g) * FF_DIM + kq;
        bSrc[i] = w2t + ((size_t)e * D_DIM + (size_t)(n0 + row)) * FF_DIM + kq;
        aDst[i] = &As[ch * 512];
        bDst[i] = &Bs[ch * 512];
    }

    const int wm = (wid >> 1) * 64;
    const int wn = (wid & 1) * 64;
    const int fr = lane & 15;
    const int fk = (lane >> 4) * 8;

    f32x4 acc[4][4];
    const f32x4 z4 = {0.f, 0.f, 0.f, 0.f};
    #pragma unroll
    for (int i = 0; i < 4; i++)
        #pragma unroll
        for (int j = 0; j < 4; j++) acc[i][j] = z4;

    for (int k0 = 0; k0 < FF_DIM; k0 += 32) {
        __syncthreads();
        #pragma unroll
        for (int i = 0; i < 2; i++) {
            GLOAD16(aSrc[i] + k0, aDst[i]);
            GLOAD16(bSrc[i] + k0, bDst[i]);
        }
        __syncthreads();

        bf16x8 af[4], bf_[4];
        #pragma unroll
        for (int i = 0; i < 4; i++) af[i] = *(const bf16x8*)&As[(wm + i * 16 + fr) * 32 + fk];
        #pragma unroll
        for (int j = 0; j < 4; j++) bf_[j] = *(const bf16x8*)&Bs[(wn + j * 16 + fr) * 32 + fk];
        #pragma unroll
        for (int i = 0; i < 4; i++)
            #pragma unroll
            for (int j = 0; j < 4; j++)
                acc[i][j] = __builtin_amdgcn_mfma_f32_16x16x32_bf16(af[i], bf_[j], acc[i][j], 0, 0, 0);
    }

    const float* b2p = b2v + (size_t)e * D_DIM + n0;
    #pragma unroll
    for (int i = 0; i < 4; i++) {
        const int rl = wm + i * 16 + (lane >> 4) * 4;
        #pragma unroll
        for (int r = 0; r < 4; r++) {
            const int g = m0 + rl + r;
            if (g < count) {
                const int token = row_token[rbase + g];
                const int slot  = row_slot[rbase + g];
                const float w   = row_weight[rbase + g];
                float* orow = contrib + ((size_t)slot * T_TOK + token) * D_DIM + n0;
                #pragma unroll
                for (int j = 0; j < 4; j++) {
                    const int col = wn + j * 16 + fr;
                    orow[col] = w * (acc[i][j][r] + b2p[col]);
                }
            }
        }
    }
}

__global__ void k_combine(const float* __restrict__ contrib, float* __restrict__ out) {
    int i = blockIdx.x * blockDim.x + threadIdx.x;
    const f32x4* c0 = (const f32x4*)contrib;
    const f32x4* c1 = c0 + ((size_t)T_TOK * D_DIM / 4);
    f32x4* o = (f32x4*)out;
    o[i] = c0[i] + c1[i];
}

// ---------------- launch ----------------

extern "C" void kernel_launch(void* const* d_in, const int* in_sizes, int n_in,
                              void* d_out, int out_size, void* d_ws, size_t ws_size,
                              hipStream_t stream)
{
    (void)in_sizes; (void)n_in; (void)out_size; (void)ws_size;
    const float* x  = (const float*)d_in[0];
    const float* Wr = (const float*)d_in[1];
    const float* W1 = (const float*)d_in[2];
    const float* b1 = (const float*)d_in[3];
    const float* Wg = (const float*)d_in[4];
    const float* bg = (const float*)d_in[5];
    const float* W2 = (const float*)d_in[6];
    const float* b2 = (const float*)d_in[7];
    float* out = (float*)d_out;

    char* ws = (char*)d_ws;
    u16* xbf = (u16*)ws;             ws += (size_t)T_TOK * D_DIM * sizeof(u16);
    u16* w1t = (u16*)ws;             ws += (size_t)E_EXP * D_DIM * FF_DIM * sizeof(u16);
    u16* wgt = (u16*)ws;             ws += (size_t)E_EXP * D_DIM * FF_DIM * sizeof(u16);
    u16* w2t = (u16*)ws;             ws += (size_t)E_EXP * D_DIM * FF_DIM * sizeof(u16);
    u16* hg = (u16*)ws;              ws += (size_t)NROWS * FF_DIM * sizeof(u16);
    int* tok_e = (int*)ws;           ws += (size_t)T_TOK * 2 * sizeof(int);
    float* tok_w = (float*)ws;       ws += (size_t)T_TOK * 2 * sizeof(float);
    int* row_token = (int*)ws;       ws += (size_t)NROWS * sizeof(int);
    int* row_slot = (int*)ws;        ws += (size_t)NROWS * sizeof(int);
    float* row_weight = (float*)ws;  ws += (size_t)NROWS * sizeof(float);
    int* cnt = (int*)ws;             ws += 8 * sizeof(int);
    int* basep = (int*)ws;           ws += 8 * sizeof(int);
    int* cursor = (int*)ws;          ws += 8 * sizeof(int);
    float* probsum = (float*)ws;     ws += 8 * sizeof(float);
    // contrib aliases w1t (pass2/combine no longer need W1t)
    float* contrib = (float*)w1t;

    k_init<<<1, 64, 0, stream>>>(cnt, probsum);
    k_cvt_x<<<(T_TOK * D_DIM / 8) / 256, 256, 0, stream>>>(x, xbf);
    k_cvt_wt<<<dim3(FF_DIM / 64, D_DIM / 64, 2 * E_EXP), 256, 0, stream>>>(W1, Wg, w1t, wgt);
    k_cvt_w2<<<dim3(D_DIM / 64, FF_DIM / 64, E_EXP), 256, 0, stream>>>(W2, w2t);
    k_router<<<T_TOK / 4, 256, 0, stream>>>(x, Wr, tok_e, tok_w, cnt, probsum);
    k_prefix<<<1, 64, 0, stream>>>(cnt, probsum, basep, cursor, out + (size_t)T_TOK * D_DIM);
    k_assign<<<T_TOK / 256, 256, 0, stream>>>(tok_e, tok_w, basep, cursor, row_token, row_slot, row_weight);
    k_pass1<<<dim3(FF_DIM / 128, 32, E_EXP), 256, 0, stream>>>(xbf, w1t, wgt, b1, bg, cnt, basep, row_token, hg);
    k_pass2<<<dim3(D_DIM / 128, 32, E_EXP), 256, 0, stream>>>(hg, w2t, b2, cnt, basep, row_token, row_slot, row_weight, contrib);
    k_combine<<<(T_TOK * D_DIM / 4) / 256, 256, 0, stream>>>(contrib, out);
}